// Round 1
// baseline (2896.718 us; speedup 1.0000x reference)
//
#include <hip/hip_runtime.h>
#include <math.h>

#define B 4
#define P 32768
#define C 8
#define F 32
#define D 64
#define H 64

// ---------------------------------------------------------------------------
// Precompute (per (b,c), independent of points):
//   z_dir[b,c,f,e] = sum_d z[b,c,f,d] * W_dir[d,e]
//   z_inv[b,c,e]   = sum_f z[b,c,f,e] * z_dir[b,c,f,e]
//   ZW[b,c,f,j]    = sum_d z[b,c,f,d] * W0[1+d, j]     (fuses net_z @ W0)
//   zc[b,c,j]      = b0[j] + sum_e z_inv[b,c,e] * W0[65+e, j]
// One block per (b,c), 64 threads (thread = output channel).
// ---------------------------------------------------------------------------
__global__ void precompute_kernel(const float* __restrict__ z,
                                  const float* __restrict__ W_dir,
                                  const float* __restrict__ W0,
                                  const float* __restrict__ b0,
                                  float* __restrict__ ZW,
                                  float* __restrict__ zc)
{
    const int bc = blockIdx.x;            // 0 .. B*C-1
    const int t  = threadIdx.x;           // 0 .. 63
    const float* zb = z + (size_t)bc * F * D;

    __shared__ float zl[F][D];
    __shared__ float zinv[D];

    for (int i = t; i < F * D; i += 64) zl[i / D][i % D] = zb[i];
    __syncthreads();

    // z_inv for channel e = t
    float zi = 0.f;
    for (int f = 0; f < F; ++f) {
        float zd = 0.f;
        for (int d = 0; d < D; ++d) zd += zl[f][d] * W_dir[d * D + t];
        zi += zl[f][t] * zd;
    }
    zinv[t] = zi;
    __syncthreads();

    // ZW[f][j], j = t
    for (int f = 0; f < F; ++f) {
        float acc = 0.f;
        for (int d = 0; d < D; ++d) acc += zl[f][d] * W0[(1 + d) * H + t];
        ZW[((size_t)bc * F + f) * H + t] = acc;
    }
    // zc[j], j = t
    float acc = b0[t];
    for (int e = 0; e < D; ++e) acc += zinv[e] * W0[(65 + e) * H + t];
    zc[(size_t)bc * H + t] = acc;
}

// ---------------------------------------------------------------------------
// Main kernel: one thread per point. All weight accesses are wave-uniform
// (scalar loads, v_fmac with SGPR operand). Activations live in registers
// (all j/k/f loops fully unrolled -> static indexing only).
// ---------------------------------------------------------------------------
__global__ __launch_bounds__(256, 2)
void main_kernel(const float* __restrict__ p,      // (B,P,3)
                 const float* __restrict__ pos,    // (B,3)
                 const float* __restrict__ W_feat, // (3,F)
                 const float* __restrict__ W0,     // (129,H) (row 0 used here)
                 const float* __restrict__ ZW,     // (B,C,F,H) precomputed
                 const float* __restrict__ zc,     // (B,C,H)  precomputed
                 const float* __restrict__ Wa,     // (5,H,H)
                 const float* __restrict__ ba,     // (5,H)
                 const float* __restrict__ Wb,     // (5,H,H)
                 const float* __restrict__ bb,     // (5,H)
                 const float* __restrict__ Wout,   // (H,1)
                 const float* __restrict__ bout,   // (1,)
                 float* __restrict__ out)          // (B,P)
{
    const int b  = blockIdx.y;
    const int pt = blockIdx.x * blockDim.x + threadIdx.x;

    // center + eval-mode norm clamp
    const float* pp = p + ((size_t)b * P + pt) * 3;
    float px = pp[0] - pos[b * 3 + 0];
    float py = pp[1] - pos[b * 3 + 1];
    float pz = pp[2] - pos[b * 3 + 2];
    float nrm = sqrtf(px * px + py * py + pz * pz);
    if (nrm > 0.5f) { float s = 0.5f / nrm; px *= s; py *= s; pz *= s; }

    // p_ext = p @ W_feat  (3 x F), W_feat wave-uniform
    float pe[F];
#pragma unroll
    for (int f = 0; f < F; ++f)
        pe[f] = px * W_feat[f] + py * W_feat[F + f] + pz * W_feat[2 * F + f];

    float s2 = 0.f;
#pragma unroll
    for (int f = 0; f < F; ++f) s2 += pe[f] * pe[f];

    float pooled[H];
#pragma unroll
    for (int j = 0; j < H; ++j) pooled[j] = -INFINITY;

    // ---- per-channel-c: h0 = [s2, net_z, z_inv] @ W0 + b0 (via ZW/zc), block 0, max-pool
    for (int c = 0; c < C; ++c) {
        const float* zwc = ZW + ((size_t)(b * C + c)) * F * H;
        const float* zcc = zc + (size_t)(b * C + c) * H;

        float h0[H];
#pragma unroll
        for (int j = 0; j < H; ++j) h0[j] = zcc[j] + s2 * W0[j];
#pragma unroll
        for (int f = 0; f < F; ++f) {
            float a = pe[f];
#pragma unroll
            for (int j = 0; j < H; ++j) h0[j] += a * zwc[f * H + j];
        }

        // residual block 0 (pre-pool): h = relu(h0)@Wa0+ba0 ; h0 += bb0 + relu(h)@Wb0
        float h[H];
#pragma unroll
        for (int j = 0; j < H; ++j) h[j] = ba[j];
#pragma unroll
        for (int k = 0; k < H; ++k) {
            float a = fmaxf(h0[k], 0.f);
#pragma unroll
            for (int j = 0; j < H; ++j) h[j] += a * Wa[k * H + j];
        }
#pragma unroll
        for (int j = 0; j < H; ++j) h0[j] += bb[j];
#pragma unroll
        for (int k = 0; k < H; ++k) {
            float a = fmaxf(h[k], 0.f);
#pragma unroll
            for (int j = 0; j < H; ++j) h0[j] += a * Wb[k * H + j];
        }
#pragma unroll
        for (int j = 0; j < H; ++j) pooled[j] = fmaxf(pooled[j], h0[j]);
    }

    // ---- residual blocks 1..4 on pooled (B,P,H)
    for (int i = 1; i < 5; ++i) {
        const float* Wai = Wa + (size_t)i * H * H;
        const float* bai = ba + (size_t)i * H;
        const float* Wbi = Wb + (size_t)i * H * H;
        const float* bbi = bb + (size_t)i * H;

        float h[H];
#pragma unroll
        for (int j = 0; j < H; ++j) h[j] = bai[j];
#pragma unroll
        for (int k = 0; k < H; ++k) {
            float a = fmaxf(pooled[k], 0.f);
#pragma unroll
            for (int j = 0; j < H; ++j) h[j] += a * Wai[k * H + j];
        }
#pragma unroll
        for (int j = 0; j < H; ++j) pooled[j] += bbi[j];
#pragma unroll
        for (int k = 0; k < H; ++k) {
            float a = fmaxf(h[k], 0.f);
#pragma unroll
            for (int j = 0; j < H; ++j) pooled[j] += a * Wbi[k * H + j];
        }
    }

    // output head
    float o = bout[0];
#pragma unroll
    for (int j = 0; j < H; ++j) o += fmaxf(pooled[j], 0.f) * Wout[j];

    out[(size_t)b * P + pt] = o;
}

extern "C" void kernel_launch(void* const* d_in, const int* in_sizes, int n_in,
                              void* d_out, int out_size, void* d_ws, size_t ws_size,
                              hipStream_t stream) {
    const float* z      = (const float*)d_in[0];
    const float* pos    = (const float*)d_in[1];
    const float* p      = (const float*)d_in[2];
    const float* W_feat = (const float*)d_in[3];
    const float* W_dir  = (const float*)d_in[4];
    const float* W0     = (const float*)d_in[5];
    const float* b0     = (const float*)d_in[6];
    const float* Wa     = (const float*)d_in[7];
    const float* ba     = (const float*)d_in[8];
    const float* Wb     = (const float*)d_in[9];
    const float* bb     = (const float*)d_in[10];
    const float* Wout   = (const float*)d_in[11];
    const float* bout   = (const float*)d_in[12];
    float* out = (float*)d_out;

    float* ZW = (float*)d_ws;                    // B*C*F*H floats
    float* zc = ZW + (size_t)B * C * F * H;      // B*C*H floats

    precompute_kernel<<<B * C, 64, 0, stream>>>(z, W_dir, W0, b0, ZW, zc);

    dim3 grid(P / 256, B);
    main_kernel<<<grid, 256, 0, stream>>>(p, pos, W_feat, W0, ZW, zc,
                                          Wa, ba, Wb, bb, Wout, bout, out);
}

// Round 2
// 1726.902 us; speedup vs baseline: 1.6774x; 1.6774x over previous
//
#include <hip/hip_runtime.h>
#include <math.h>

#define B 4
#define P 32768
#define C 8
#define F 32
#define D 64
#define H 64

// ---------------------------------------------------------------------------
// Precompute (per (b,c), independent of points):
//   z_dir[b,c,f,e] = sum_d z[b,c,f,d] * W_dir[d,e]
//   z_inv[b,c,e]   = sum_f z[b,c,f,e] * z_dir[b,c,f,e]
//   ZW[b,c,f,j]    = sum_d z[b,c,f,d] * W0[1+d, j]     (fuses net_z @ W0)
//   zc[b,c,j]      = b0[j] + sum_e z_inv[b,c,e] * W0[65+e, j]
// ---------------------------------------------------------------------------
__global__ void precompute_kernel(const float* __restrict__ z,
                                  const float* __restrict__ W_dir,
                                  const float* __restrict__ W0,
                                  const float* __restrict__ b0,
                                  float* __restrict__ ZW,
                                  float* __restrict__ zc)
{
    const int bc = blockIdx.x;            // 0 .. B*C-1
    const int t  = threadIdx.x;           // 0 .. 63
    const float* zb = z + (size_t)bc * F * D;

    __shared__ float zl[F][D];
    __shared__ float zinv[D];

    for (int i = t; i < F * D; i += 64) zl[i / D][i % D] = zb[i];
    __syncthreads();

    float zi = 0.f;
    for (int f = 0; f < F; ++f) {
        float zd = 0.f;
        for (int d = 0; d < D; ++d) zd += zl[f][d] * W_dir[d * D + t];
        zi += zl[f][t] * zd;
    }
    zinv[t] = zi;
    __syncthreads();

    for (int f = 0; f < F; ++f) {
        float acc = 0.f;
        for (int d = 0; d < D; ++d) acc += zl[f][d] * W0[(1 + d) * H + t];
        ZW[((size_t)bc * F + f) * H + t] = acc;
    }
    float acc = b0[t];
    for (int e = 0; e < D; ++e) acc += zinv[e] * W0[(65 + e) * H + t];
    zc[(size_t)bc * H + t] = acc;
}

// ---------------------------------------------------------------------------
// Main kernel: one thread per point. Weight/ZW accesses are wave-uniform
// (scalar loads). Live register arrays capped at pooled[64]+x[64]+h[64]=192
// floats; pe[] is rematerialized per f (3 FMAs amortized over 64).
// __launch_bounds__(256,1): VGPR cap 512 — R1 showed (256,2) capped at 128
// and spilled 1.35 GB to scratch/HBM.
// ---------------------------------------------------------------------------
__global__ __launch_bounds__(256, 1)
void main_kernel(const float* __restrict__ p,      // (B,P,3)
                 const float* __restrict__ pos,    // (B,3)
                 const float* __restrict__ W_feat, // (3,F)
                 const float* __restrict__ W0,     // (129,H) row 0 used
                 const float* __restrict__ ZW,     // (B,C,F,H)
                 const float* __restrict__ zc,     // (B,C,H)
                 const float* __restrict__ Wa,     // (5,H,H)
                 const float* __restrict__ ba,     // (5,H)
                 const float* __restrict__ Wb,     // (5,H,H)
                 const float* __restrict__ bb,     // (5,H)
                 const float* __restrict__ Wout,   // (H,1)
                 const float* __restrict__ bout,   // (1,)
                 float* __restrict__ out)          // (B,P)
{
    const int b  = blockIdx.y;
    const int pt = blockIdx.x * blockDim.x + threadIdx.x;

    const float* pp = p + ((size_t)b * P + pt) * 3;
    float px = pp[0] - pos[b * 3 + 0];
    float py = pp[1] - pos[b * 3 + 1];
    float pz = pp[2] - pos[b * 3 + 2];
    float nrm = sqrtf(px * px + py * py + pz * pz);
    if (nrm > 0.5f) { float s = 0.5f / nrm; px *= s; py *= s; pz *= s; }

    // s2 = |p @ W_feat|^2  (pe rematerialized, not stored)
    float s2 = 0.f;
    for (int f = 0; f < F; ++f) {
        float a = px * W_feat[f] + py * W_feat[F + f] + pz * W_feat[2 * F + f];
        s2 += a * a;
    }

    float pooled[H];
#pragma unroll
    for (int j = 0; j < H; ++j) pooled[j] = -INFINITY;

    for (int c = 0; c < C; ++c) {
        const float* zwc = ZW + ((size_t)(b * C + c)) * F * H;
        const float* zcc = zc + (size_t)(b * C + c) * H;

        float x[H];  // h0
#pragma unroll
        for (int j = 0; j < H; ++j) x[j] = zcc[j] + s2 * W0[j];

        for (int f = 0; f < F; ++f) {
            float a = px * W_feat[f] + py * W_feat[F + f] + pz * W_feat[2 * F + f];
#pragma unroll
            for (int j = 0; j < H; ++j) x[j] += a * zwc[f * H + j];
        }

        // residual block 0: h = relu(x)@Wa0+ba0 ; x += bb0 + relu(h)@Wb0
        float h[H];
#pragma unroll
        for (int j = 0; j < H; ++j) h[j] = ba[j];
#pragma unroll
        for (int k = 0; k < H; ++k) {
            float a = fmaxf(x[k], 0.f);
#pragma unroll
            for (int j = 0; j < H; ++j) h[j] += a * Wa[k * H + j];
        }
#pragma unroll
        for (int j = 0; j < H; ++j) x[j] += bb[j];
#pragma unroll
        for (int k = 0; k < H; ++k) {
            float a = fmaxf(h[k], 0.f);
#pragma unroll
            for (int j = 0; j < H; ++j) x[j] += a * Wb[k * H + j];
        }
#pragma unroll
        for (int j = 0; j < H; ++j) pooled[j] = fmaxf(pooled[j], x[j]);
    }

    // residual blocks 1..4 on pooled
    for (int i = 1; i < 5; ++i) {
        const float* Wai = Wa + (size_t)i * H * H;
        const float* bai = ba + (size_t)i * H;
        const float* Wbi = Wb + (size_t)i * H * H;
        const float* bbi = bb + (size_t)i * H;

        float h[H];
#pragma unroll
        for (int j = 0; j < H; ++j) h[j] = bai[j];
#pragma unroll
        for (int k = 0; k < H; ++k) {
            float a = fmaxf(pooled[k], 0.f);
#pragma unroll
            for (int j = 0; j < H; ++j) h[j] += a * Wai[k * H + j];
        }
#pragma unroll
        for (int j = 0; j < H; ++j) pooled[j] += bbi[j];
#pragma unroll
        for (int k = 0; k < H; ++k) {
            float a = fmaxf(h[k], 0.f);
#pragma unroll
            for (int j = 0; j < H; ++j) pooled[j] += a * Wbi[k * H + j];
        }
    }

    float o = bout[0];
#pragma unroll
    for (int j = 0; j < H; ++j) o += fmaxf(pooled[j], 0.f) * Wout[j];

    out[(size_t)b * P + pt] = o;
}

extern "C" void kernel_launch(void* const* d_in, const int* in_sizes, int n_in,
                              void* d_out, int out_size, void* d_ws, size_t ws_size,
                              hipStream_t stream) {
    const float* z      = (const float*)d_in[0];
    const float* pos    = (const float*)d_in[1];
    const float* p      = (const float*)d_in[2];
    const float* W_feat = (const float*)d_in[3];
    const float* W_dir  = (const float*)d_in[4];
    const float* W0     = (const float*)d_in[5];
    const float* b0     = (const float*)d_in[6];
    const float* Wa     = (const float*)d_in[7];
    const float* ba     = (const float*)d_in[8];
    const float* Wb     = (const float*)d_in[9];
    const float* bb     = (const float*)d_in[10];
    const float* Wout   = (const float*)d_in[11];
    const float* bout   = (const float*)d_in[12];
    float* out = (float*)d_out;

    float* ZW = (float*)d_ws;                    // B*C*F*H floats
    float* zc = ZW + (size_t)B * C * F * H;      // B*C*H floats

    precompute_kernel<<<B * C, 64, 0, stream>>>(z, W_dir, W0, b0, ZW, zc);

    dim3 grid(P / 256, B);
    main_kernel<<<grid, 256, 0, stream>>>(p, pos, W_feat, W0, ZW, zc,
                                          Wa, ba, Wb, bb, Wout, bout, out);
}

// Round 3
// 281.951 us; speedup vs baseline: 10.2739x; 6.1248x over previous
//
#include <hip/hip_runtime.h>
#include <math.h>

#define B 4
#define P 32768
#define C 8
#define F 32
#define D 64
#define H 64

typedef __attribute__((ext_vector_type(8))) short bf16x8;
typedef __attribute__((ext_vector_type(4))) float f32x4;

__device__ __host__ __forceinline__ short f2bf(float f) {
    union { float f; unsigned u; } v; v.f = f;
    unsigned r = (v.u + 0x7FFFu + ((v.u >> 16) & 1u)) >> 16;   // RNE
    return (short)r;
}

// ---------------------------------------------------------------------------
// Precompute per (b,c) the bf16 B-matrix for the fused X-build GEMM,
// stored n-major (row n, col k), K=64:
//   k in [0,32):  ZW[k][n] = sum_d z[b,c,k,d] * W0[1+d, n]
//   k == 32:      W0[0, n]                  (multiplies s2)
//   k == 33:      b0[n] + z_inv @ W0[65:,n] (multiplies 1)
//   k >= 34:      0
// ---------------------------------------------------------------------------
__global__ void precompute_kernel(const float* __restrict__ z,
                                  const float* __restrict__ W_dir,
                                  const float* __restrict__ W0,
                                  const float* __restrict__ b0,
                                  short* __restrict__ Bxt)
{
    const int bc = blockIdx.x;            // 0 .. B*C-1
    const int t  = threadIdx.x;           // 0 .. 63  (= output col n)
    const float* zb = z + (size_t)bc * F * D;

    __shared__ float zl[F][D];
    __shared__ float zinv[D];

    for (int i = t; i < F * D; i += 64) zl[i / D][i % D] = zb[i];
    __syncthreads();

    float zi = 0.f;
    for (int f = 0; f < F; ++f) {
        float zd = 0.f;
        for (int d = 0; d < D; ++d) zd += zl[f][d] * W_dir[d * D + t];
        zi += zl[f][t] * zd;
    }
    zinv[t] = zi;
    __syncthreads();

    short* brow = Bxt + ((size_t)bc * 64 + t) * 64;     // row n = t
    for (int k = 0; k < F; ++k) {
        float acc = 0.f;
        for (int d = 0; d < D; ++d) acc += zl[k][d] * W0[(1 + d) * H + t];
        brow[k] = f2bf(acc);
    }
    brow[32] = f2bf(W0[t]);                              // W0 row 0
    float zc = b0[t];
    for (int e = 0; e < D; ++e) zc += zinv[e] * W0[(65 + e) * H + t];
    brow[33] = f2bf(zc);
    for (int k = 34; k < 64; ++k) brow[k] = 0;
}

// ---------------------------------------------------------------------------
// Transpose + bf16-convert Wa/Wb to n-major so B-fragments are contiguous
// 16B loads:  Wt[i][n][k] = W[i][k][n]
// ---------------------------------------------------------------------------
__global__ void wtrans_kernel(const float* __restrict__ Wa,
                              const float* __restrict__ Wb,
                              short* __restrict__ Wat,
                              short* __restrict__ Wbt)
{
    int idx = blockIdx.x * 256 + threadIdx.x;   // < 5*64*64
    int i = idx >> 12, r = idx & 4095, k = r >> 6, n = r & 63;
    int o = (i << 12) + (n << 6) + k;
    Wat[o] = f2bf(Wa[idx]);
    Wbt[o] = f2bf(Wb[idx]);
}

// ---------------------------------------------------------------------------
// Main: 4 waves/block, each wave owns 16 points end-to-end (no barriers).
// All GEMM stages are 16x64 @ 64x64 via mfma_f32_16x16x32_bf16:
//   A-frag: row m=lane&15, k=quad*8+j  (from per-wave LDS, 2-way-conflict-free)
//   B-frag: col n=lane&15, k=quad*8+j  (16B global loads from n-major weights)
//   C/D   : col=lane&15,  row=quad*4+reg
// Residual/pool state stays in fp32 C-layout registers.
// ---------------------------------------------------------------------------
#define RS 72    // LDS row stride in shorts (64 + 8 pad -> b128 reads 2-way only)

__global__ __launch_bounds__(256, 1)
void main_kernel(const float* __restrict__ p,      // (B,P,3)
                 const float* __restrict__ pos,    // (B,3)
                 const float* __restrict__ W_feat, // (3,F)
                 const short* __restrict__ Bxt,    // (B,C,64n,64k) bf16
                 const short* __restrict__ Wat,    // (5,64n,64k) bf16
                 const short* __restrict__ Wbt,    // (5,64n,64k) bf16
                 const float* __restrict__ ba,     // (5,H)
                 const float* __restrict__ bb,     // (5,H)
                 const float* __restrict__ Wout,   // (H,1)
                 const float* __restrict__ bout,   // (1,)
                 float* __restrict__ out)          // (B,P)
{
    const int wave = threadIdx.x >> 6;
    const int lane = threadIdx.x & 63;
    const int quad = lane >> 4;
    const int l16  = lane & 15;
    const int b    = blockIdx.y;
    const int tileBase = blockIdx.x * 64;
    const int ptRow = tileBase + wave * 16 + l16;   // point whose A-frag this lane helps hold

    __shared__ short lds[4 * 2 * 16 * RS];
    short* bufX = lds + wave * (2 * 16 * RS);
    short* bufH = bufX + 16 * RS;

    // ---- point features (4 lanes per point compute redundantly)
    const float* pp = p + ((size_t)b * P + ptRow) * 3;
    float px = pp[0] - pos[b * 3 + 0];
    float py = pp[1] - pos[b * 3 + 1];
    float pz = pp[2] - pos[b * 3 + 2];
    float nrm = sqrtf(px * px + py * py + pz * pz);
    if (nrm > 0.5f) { float s = 0.5f / nrm; px *= s; py *= s; pz *= s; }

    float pe[8]; float s2 = 0.f;
#pragma unroll
    for (int j = 0; j < 8; ++j) {
        int k = quad * 8 + j;
        float a = px * W_feat[k] + py * W_feat[F + k] + pz * W_feat[2 * F + k];
        pe[j] = a; s2 += a * a;
    }
    s2 += __shfl_xor(s2, 16);
    s2 += __shfl_xor(s2, 32);                      // full s2 of point l16

    bf16x8 a0, a1;                                 // A' frags: k<32 = pe, k=32 s2, k=33 one
#pragma unroll
    for (int j = 0; j < 8; ++j) a0[j] = f2bf(pe[j]);
#pragma unroll
    for (int j = 0; j < 8; ++j) a1[j] = 0;
    if (quad == 0) { a1[0] = f2bf(s2); a1[1] = f2bf(1.0f); }

    // ---- per-lane bias / head-weight preload (col n = nt*16 + l16)
    float ba_r[5][4], bb_r[5][4], wo_r[4];
#pragma unroll
    for (int i = 0; i < 5; ++i)
#pragma unroll
        for (int nt = 0; nt < 4; ++nt) {
            ba_r[i][nt] = ba[i * H + nt * 16 + l16];
            bb_r[i][nt] = bb[i * H + nt * 16 + l16];
        }
#pragma unroll
    for (int nt = 0; nt < 4; ++nt) wo_r[nt] = Wout[nt * 16 + l16];

    f32x4 pooled[4];
#pragma unroll
    for (int nt = 0; nt < 4; ++nt)
        pooled[nt] = (f32x4){-1e30f, -1e30f, -1e30f, -1e30f};

    // ================= c-loop: X-build + residual block 0 + max-pool =======
    for (int c = 0; c < C; ++c) {
        const short* bx = Bxt + ((size_t)(b * C + c)) * 64 * 64;

        f32x4 x[4];
#pragma unroll
        for (int nt = 0; nt < 4; ++nt) {
            bf16x8 b0f = *(const bf16x8*)(bx + (nt * 16 + l16) * 64 + quad * 8);
            bf16x8 b1f = *(const bf16x8*)(bx + (nt * 16 + l16) * 64 + 32 + quad * 8);
            f32x4 acc = (f32x4){0.f, 0.f, 0.f, 0.f};
            acc = __builtin_amdgcn_mfma_f32_16x16x32_bf16(a0, b0f, acc, 0, 0, 0);
            acc = __builtin_amdgcn_mfma_f32_16x16x32_bf16(a1, b1f, acc, 0, 0, 0);
            x[nt] = acc;
        }

        // relu(x) -> bufX (A-layout for next GEMM)
#pragma unroll
        for (int nt = 0; nt < 4; ++nt)
#pragma unroll
            for (int r = 0; r < 4; ++r)
                bufX[(quad * 4 + r) * RS + nt * 16 + l16] = f2bf(fmaxf(x[nt][r], 0.f));

        bf16x8 xa0 = *(const bf16x8*)(bufX + l16 * RS + quad * 8);
        bf16x8 xa1 = *(const bf16x8*)(bufX + l16 * RS + 32 + quad * 8);

        f32x4 h[4];
#pragma unroll
        for (int nt = 0; nt < 4; ++nt) {
            bf16x8 w0f = *(const bf16x8*)(Wat + (nt * 16 + l16) * 64 + quad * 8);
            bf16x8 w1f = *(const bf16x8*)(Wat + (nt * 16 + l16) * 64 + 32 + quad * 8);
            f32x4 acc = (f32x4){ba_r[0][nt], ba_r[0][nt], ba_r[0][nt], ba_r[0][nt]};
            acc = __builtin_amdgcn_mfma_f32_16x16x32_bf16(xa0, w0f, acc, 0, 0, 0);
            acc = __builtin_amdgcn_mfma_f32_16x16x32_bf16(xa1, w1f, acc, 0, 0, 0);
            h[nt] = acc;
        }

        // relu(h) -> bufH
#pragma unroll
        for (int nt = 0; nt < 4; ++nt)
#pragma unroll
            for (int r = 0; r < 4; ++r)
                bufH[(quad * 4 + r) * RS + nt * 16 + l16] = f2bf(fmaxf(h[nt][r], 0.f));

        bf16x8 ha0 = *(const bf16x8*)(bufH + l16 * RS + quad * 8);
        bf16x8 ha1 = *(const bf16x8*)(bufH + l16 * RS + 32 + quad * 8);

#pragma unroll
        for (int nt = 0; nt < 4; ++nt) {
            bf16x8 w0f = *(const bf16x8*)(Wbt + (nt * 16 + l16) * 64 + quad * 8);
            bf16x8 w1f = *(const bf16x8*)(Wbt + (nt * 16 + l16) * 64 + 32 + quad * 8);
            f32x4 acc = x[nt];
#pragma unroll
            for (int r = 0; r < 4; ++r) acc[r] += bb_r[0][nt];
            acc = __builtin_amdgcn_mfma_f32_16x16x32_bf16(ha0, w0f, acc, 0, 0, 0);
            acc = __builtin_amdgcn_mfma_f32_16x16x32_bf16(ha1, w1f, acc, 0, 0, 0);
#pragma unroll
            for (int r = 0; r < 4; ++r)
                pooled[nt][r] = fmaxf(pooled[nt][r], acc[r]);
        }
    }

    // ================= residual blocks 1..4 on pooled ======================
#pragma unroll
    for (int i = 1; i < 5; ++i) {
        const short* wa = Wat + i * H * H;
        const short* wb = Wbt + i * H * H;

#pragma unroll
        for (int nt = 0; nt < 4; ++nt)
#pragma unroll
            for (int r = 0; r < 4; ++r)
                bufX[(quad * 4 + r) * RS + nt * 16 + l16] = f2bf(fmaxf(pooled[nt][r], 0.f));

        bf16x8 xa0 = *(const bf16x8*)(bufX + l16 * RS + quad * 8);
        bf16x8 xa1 = *(const bf16x8*)(bufX + l16 * RS + 32 + quad * 8);

        f32x4 h[4];
#pragma unroll
        for (int nt = 0; nt < 4; ++nt) {
            bf16x8 w0f = *(const bf16x8*)(wa + (nt * 16 + l16) * 64 + quad * 8);
            bf16x8 w1f = *(const bf16x8*)(wa + (nt * 16 + l16) * 64 + 32 + quad * 8);
            f32x4 acc = (f32x4){ba_r[i][nt], ba_r[i][nt], ba_r[i][nt], ba_r[i][nt]};
            acc = __builtin_amdgcn_mfma_f32_16x16x32_bf16(xa0, w0f, acc, 0, 0, 0);
            acc = __builtin_amdgcn_mfma_f32_16x16x32_bf16(xa1, w1f, acc, 0, 0, 0);
            h[nt] = acc;
        }

#pragma unroll
        for (int nt = 0; nt < 4; ++nt)
#pragma unroll
            for (int r = 0; r < 4; ++r)
                bufH[(quad * 4 + r) * RS + nt * 16 + l16] = f2bf(fmaxf(h[nt][r], 0.f));

        bf16x8 ha0 = *(const bf16x8*)(bufH + l16 * RS + quad * 8);
        bf16x8 ha1 = *(const bf16x8*)(bufH + l16 * RS + 32 + quad * 8);

#pragma unroll
        for (int nt = 0; nt < 4; ++nt) {
            bf16x8 w0f = *(const bf16x8*)(wb + (nt * 16 + l16) * 64 + quad * 8);
            bf16x8 w1f = *(const bf16x8*)(wb + (nt * 16 + l16) * 64 + 32 + quad * 8);
            f32x4 acc = pooled[nt];
#pragma unroll
            for (int r = 0; r < 4; ++r) acc[r] += bb_r[i][nt];
            acc = __builtin_amdgcn_mfma_f32_16x16x32_bf16(ha0, w0f, acc, 0, 0, 0);
            acc = __builtin_amdgcn_mfma_f32_16x16x32_bf16(ha1, w1f, acc, 0, 0, 0);
            pooled[nt] = acc;
        }
    }

    // ================= head: out = relu(x) @ Wout + bout ===================
    float o[4];
#pragma unroll
    for (int r = 0; r < 4; ++r) {
        float v = 0.f;
#pragma unroll
        for (int nt = 0; nt < 4; ++nt) v += fmaxf(pooled[nt][r], 0.f) * wo_r[nt];
        v += __shfl_xor(v, 1);
        v += __shfl_xor(v, 2);
        v += __shfl_xor(v, 4);
        v += __shfl_xor(v, 8);
        o[r] = v + bout[0];
    }
    if (l16 == 0) {
        float4 o4 = make_float4(o[0], o[1], o[2], o[3]);
        *(float4*)(out + (size_t)b * P + tileBase + wave * 16 + quad * 4) = o4;
    }
}

extern "C" void kernel_launch(void* const* d_in, const int* in_sizes, int n_in,
                              void* d_out, int out_size, void* d_ws, size_t ws_size,
                              hipStream_t stream) {
    const float* z      = (const float*)d_in[0];
    const float* pos    = (const float*)d_in[1];
    const float* p      = (const float*)d_in[2];
    const float* W_feat = (const float*)d_in[3];
    const float* W_dir  = (const float*)d_in[4];
    const float* W0     = (const float*)d_in[5];
    const float* b0     = (const float*)d_in[6];
    const float* Wa     = (const float*)d_in[7];
    const float* ba     = (const float*)d_in[8];
    const float* Wb     = (const float*)d_in[9];
    const float* bb     = (const float*)d_in[10];
    const float* Wout   = (const float*)d_in[11];
    const float* bout   = (const float*)d_in[12];
    float* out = (float*)d_out;

    short* wsS = (short*)d_ws;
    short* Bxt = wsS;                    // B*C*64*64 = 131072 shorts
    short* Wat = wsS + 32 * 4096;        // 5*4096 shorts
    short* Wbt = Wat + 5 * 4096;         // 5*4096 shorts

    precompute_kernel<<<B * C, 64, 0, stream>>>(z, W_dir, W0, b0, Bxt);
    wtrans_kernel<<<80, 256, 0, stream>>>(Wa, Wb, Wat, Wbt);

    dim3 grid(P / 64, B);
    main_kernel<<<grid, 256, 0, stream>>>(p, pos, W_feat, Bxt, Wat, Wbt,
                                          ba, bb, Wout, bout, out);
}

// Round 4
// 210.334 us; speedup vs baseline: 13.7720x; 1.3405x over previous
//
#include <hip/hip_runtime.h>
#include <math.h>

#define B 4
#define P 32768
#define C 8
#define F 32
#define D 64
#define H 64
#define RS 72   // LDS row stride in shorts

typedef __attribute__((ext_vector_type(8))) short bf16x8;
typedef __attribute__((ext_vector_type(4))) float f32x4;

__device__ __forceinline__ short f2bf(float f) {
    union { float f; unsigned u; } v; v.f = f;
    unsigned r = (v.u + 0x7FFFu + ((v.u >> 16) & 1u)) >> 16;   // RNE
    return (short)r;
}

// ---------------------------------------------------------------------------
// Merged setup kernel.
// blocks [0,32):  per-(b,c) Bxt build (K<=33 rows: ZW, W0-row0, zc; rest 0)
// blocks [32,112): Wa/Wb transpose+cvt to n-major bf16
// All n-major weight storage uses the COLUMN PERMUTATION: storage row
// s = (a%4)*16 + a/4  holds actual output column a. This makes the MFMA
// C-layout's 4 per-lane values memory-adjacent (ds_write_b64 transform).
// ---------------------------------------------------------------------------
__global__ __launch_bounds__(256)
void setup_kernel(const float* __restrict__ z,
                  const float* __restrict__ W_dir,
                  const float* __restrict__ W0,
                  const float* __restrict__ b0,
                  const float* __restrict__ Wa,
                  const float* __restrict__ Wb,
                  short* __restrict__ Bxt,
                  short* __restrict__ Wat,
                  short* __restrict__ Wbt)
{
    if (blockIdx.x >= 32) {
        int idx = (blockIdx.x - 32) * 256 + threadIdx.x;  // < 5*64*64
        int i = idx >> 12, r = idx & 4095, k = r >> 6, n = r & 63;
        int s = (n & 3) * 16 + (n >> 2);                  // permuted storage row
        int o = (i << 12) + (s << 6) + k;
        Wat[o] = f2bf(Wa[idx]);
        Wbt[o] = f2bf(Wb[idx]);
        return;
    }
    const int bc = blockIdx.x;
    const int t  = threadIdx.x & 63;     // actual output column
    const int g  = threadIdx.x >> 6;     // f-group 0..3
    const float* zb = z + (size_t)bc * F * D;

    __shared__ float zl[F][D];
    __shared__ float zp[4][D];

    for (int i = threadIdx.x; i < F * D; i += 256) zl[i >> 6][i & 63] = zb[i];
    __syncthreads();

    const int srow = (t & 3) * 16 + (t >> 2);
    short* brow = Bxt + ((size_t)bc * 64 + srow) * 64;

    float zi = 0.f;
    for (int f = g * 8; f < g * 8 + 8; ++f) {
        float z0 = 0, z1 = 0, z2 = 0, z3 = 0;
        float a0 = 0, a1 = 0, a2 = 0, a3 = 0;
        for (int d = 0; d < D; d += 4) {
            z0 += zl[f][d + 0] * W_dir[(d + 0) * D + t];
            z1 += zl[f][d + 1] * W_dir[(d + 1) * D + t];
            z2 += zl[f][d + 2] * W_dir[(d + 2) * D + t];
            z3 += zl[f][d + 3] * W_dir[(d + 3) * D + t];
            a0 += zl[f][d + 0] * W0[(1 + d + 0) * H + t];
            a1 += zl[f][d + 1] * W0[(1 + d + 1) * H + t];
            a2 += zl[f][d + 2] * W0[(1 + d + 2) * H + t];
            a3 += zl[f][d + 3] * W0[(1 + d + 3) * H + t];
        }
        zi += zl[f][t] * ((z0 + z1) + (z2 + z3));
        brow[f] = f2bf((a0 + a1) + (a2 + a3));    // ZW row f, col t (K natural)
    }
    zp[g][t] = zi;
    __syncthreads();
    if (g == 0) {
        float zall = zp[0][t] + zp[1][t] + zp[2][t] + zp[3][t];
        zp[0][t] = zall;                          // full z_inv[t]
    }
    __syncthreads();
    if (g == 0) {
        brow[32] = f2bf(W0[t]);                   // multiplies s2
        float zc = b0[t];
        for (int e = 0; e < D; ++e) zc += zp[0][e] * W0[(65 + e) * H + t];
        brow[33] = f2bf(zc);                      // multiplies 1
    } else if (g == 1) {
        for (int k = 34; k < 64; ++k) brow[k] = 0;
    }
}

// ---------------------------------------------------------------------------
// Main: 4 waves/block; each wave owns 32 points (2 m-tiles) and processes
// 2 channels concurrently in the c-loop -> 4 independent GEMM chains for
// latency hiding; weight fragments shared across all chains.
// C-layout -> A-layout transform: 4 x ds_write_b64 (col-permuted storage)
// + 2 x ds_read_b128 per tile-stage. No barriers anywhere (per-wave LDS).
// ---------------------------------------------------------------------------
__global__ __launch_bounds__(256, 1)
void main_kernel(const float* __restrict__ p,      // (B,P,3)
                 const float* __restrict__ pos,    // (B,3)
                 const float* __restrict__ W_feat, // (3,F)
                 const short* __restrict__ Bxt,    // (B,C,64s,64k) bf16 (perm cols)
                 const short* __restrict__ Wat,    // (5,64s,64k)
                 const short* __restrict__ Wbt,    // (5,64s,64k)
                 const float* __restrict__ ba,     // (5,H)
                 const float* __restrict__ bb,     // (5,H)
                 const float* __restrict__ Wout,   // (H,1)
                 const float* __restrict__ bout,   // (1,)
                 float* __restrict__ out)          // (B,P)
{
    const int wave = threadIdx.x >> 6;
    const int lane = threadIdx.x & 63;
    const int quad = lane >> 4;
    const int l16  = lane & 15;
    const int b    = blockIdx.y;
    const int base = blockIdx.x * 128 + wave * 32;

    __shared__ short lds[4][4][16 * RS];          // [wave][chain] = 36.9 KB

    // ---- point features -> A'-frags for both m-tiles
    bf16x8 a0[2], a1[2];
#pragma unroll
    for (int m = 0; m < 2; ++m) {
        const float* pp = p + ((size_t)b * P + base + m * 16 + l16) * 3;
        float px = pp[0] - pos[b * 3 + 0];
        float py = pp[1] - pos[b * 3 + 1];
        float pz = pp[2] - pos[b * 3 + 2];
        float nrm = sqrtf(px * px + py * py + pz * pz);
        if (nrm > 0.5f) { float s = 0.5f / nrm; px *= s; py *= s; pz *= s; }
        float s2 = 0.f;
#pragma unroll
        for (int j = 0; j < 8; ++j) {
            int k = quad * 8 + j;
            float a = px * W_feat[k] + py * W_feat[F + k] + pz * W_feat[2 * F + k];
            a0[m][j] = f2bf(a);
            s2 += a * a;
        }
        s2 += __shfl_xor(s2, 16);
        s2 += __shfl_xor(s2, 32);
#pragma unroll
        for (int j = 0; j < 8; ++j) a1[m][j] = 0;
        if (quad == 0) { a1[m][0] = f2bf(s2); a1[m][1] = f2bf(1.0f); }
    }

    f32x4 pooled[2][4];
#pragma unroll
    for (int m = 0; m < 2; ++m)
#pragma unroll
        for (int nt = 0; nt < 4; ++nt)
            pooled[m][nt] = (f32x4){-1e30f, -1e30f, -1e30f, -1e30f};

    const float4 ba0v = *(const float4*)(ba + 4 * l16);
    const float4 bb0v = *(const float4*)(bb + 4 * l16);

    // =============== c-loop: 2 channels at a time, 4 chains =================
    for (int cc = 0; cc < C; cc += 2) {
        // ---- stage 1: x-build (chain ch = m*2+cs)
        f32x4 x[4][4];
#pragma unroll
        for (int cs = 0; cs < 2; ++cs) {
            const short* bx = Bxt + ((size_t)(b * C + cc + cs)) * 4096;
#pragma unroll
            for (int nt = 0; nt < 4; ++nt) {
                bf16x8 b0f = *(const bf16x8*)(bx + (nt * 16 + l16) * 64 + quad * 8);
                bf16x8 b1f = *(const bf16x8*)(bx + (nt * 16 + l16) * 64 + 32 + quad * 8);
#pragma unroll
                for (int m = 0; m < 2; ++m) {
                    f32x4 acc = (f32x4){0.f, 0.f, 0.f, 0.f};
                    acc = __builtin_amdgcn_mfma_f32_16x16x32_bf16(a0[m], b0f, acc, 0, 0, 0);
                    acc = __builtin_amdgcn_mfma_f32_16x16x32_bf16(a1[m], b1f, acc, 0, 0, 0);
                    x[m * 2 + cs][nt] = acc;
                }
            }
        }

        // ---- relu(x) -> LDS (b64 writes) -> A-frags
        bf16x8 xa0[4], xa1[4];
#pragma unroll
        for (int ch = 0; ch < 4; ++ch) {
            short* buf = &lds[wave][ch][0];
#pragma unroll
            for (int r = 0; r < 4; ++r) {
                short4 w4;
                w4.x = f2bf(fmaxf(x[ch][0][r], 0.f));
                w4.y = f2bf(fmaxf(x[ch][1][r], 0.f));
                w4.z = f2bf(fmaxf(x[ch][2][r], 0.f));
                w4.w = f2bf(fmaxf(x[ch][3][r], 0.f));
                *(short4*)(buf + (quad * 4 + r) * RS + 4 * l16) = w4;
            }
        }
#pragma unroll
        for (int ch = 0; ch < 4; ++ch) {
            const short* buf = &lds[wave][ch][0];
            xa0[ch] = *(const bf16x8*)(buf + l16 * RS + quad * 8);
            xa1[ch] = *(const bf16x8*)(buf + l16 * RS + 32 + quad * 8);
        }

        // ---- stage 2: h = relu(x) @ Wa0 + ba0
        f32x4 h[4][4];
#pragma unroll
        for (int nt = 0; nt < 4; ++nt) {
            bf16x8 w0f = *(const bf16x8*)(Wat + (nt * 16 + l16) * 64 + quad * 8);
            bf16x8 w1f = *(const bf16x8*)(Wat + (nt * 16 + l16) * 64 + 32 + quad * 8);
            float bv = nt == 0 ? ba0v.x : nt == 1 ? ba0v.y : nt == 2 ? ba0v.z : ba0v.w;
#pragma unroll
            for (int ch = 0; ch < 4; ++ch) {
                f32x4 acc = (f32x4){bv, bv, bv, bv};
                acc = __builtin_amdgcn_mfma_f32_16x16x32_bf16(xa0[ch], w0f, acc, 0, 0, 0);
                acc = __builtin_amdgcn_mfma_f32_16x16x32_bf16(xa1[ch], w1f, acc, 0, 0, 0);
                h[ch][nt] = acc;
            }
        }

        // ---- relu(h) -> LDS (reuse bufs; DS pipe is in-order per wave)
        bf16x8 ha0[4], ha1[4];
#pragma unroll
        for (int ch = 0; ch < 4; ++ch) {
            short* buf = &lds[wave][ch][0];
#pragma unroll
            for (int r = 0; r < 4; ++r) {
                short4 w4;
                w4.x = f2bf(fmaxf(h[ch][0][r], 0.f));
                w4.y = f2bf(fmaxf(h[ch][1][r], 0.f));
                w4.z = f2bf(fmaxf(h[ch][2][r], 0.f));
                w4.w = f2bf(fmaxf(h[ch][3][r], 0.f));
                *(short4*)(buf + (quad * 4 + r) * RS + 4 * l16) = w4;
            }
        }
#pragma unroll
        for (int ch = 0; ch < 4; ++ch) {
            const short* buf = &lds[wave][ch][0];
            ha0[ch] = *(const bf16x8*)(buf + l16 * RS + quad * 8);
            ha1[ch] = *(const bf16x8*)(buf + l16 * RS + 32 + quad * 8);
        }

        // ---- stage 3: x += bb0 + relu(h) @ Wb0 ; max-pool
#pragma unroll
        for (int nt = 0; nt < 4; ++nt) {
            bf16x8 w0f = *(const bf16x8*)(Wbt + (nt * 16 + l16) * 64 + quad * 8);
            bf16x8 w1f = *(const bf16x8*)(Wbt + (nt * 16 + l16) * 64 + 32 + quad * 8);
            float bv = nt == 0 ? bb0v.x : nt == 1 ? bb0v.y : nt == 2 ? bb0v.z : bb0v.w;
#pragma unroll
            for (int ch = 0; ch < 4; ++ch) {
                f32x4 acc = x[ch][nt];
#pragma unroll
                for (int r = 0; r < 4; ++r) acc[r] += bv;
                acc = __builtin_amdgcn_mfma_f32_16x16x32_bf16(ha0[ch], w0f, acc, 0, 0, 0);
                acc = __builtin_amdgcn_mfma_f32_16x16x32_bf16(ha1[ch], w1f, acc, 0, 0, 0);
                const int m = ch >> 1;
#pragma unroll
                for (int r = 0; r < 4; ++r)
                    pooled[m][nt][r] = fmaxf(pooled[m][nt][r], acc[r]);
            }
        }
    }

    // =============== residual blocks 1..4 (2 chains: m-tiles) ===============
#pragma unroll
    for (int i = 1; i < 5; ++i) {
        const short* wa = Wat + i * 4096;
        const short* wb = Wbt + i * 4096;
        const float4 bai = *(const float4*)(ba + i * H + 4 * l16);
        const float4 bbi = *(const float4*)(bb + i * H + 4 * l16);

        bf16x8 xa0[2], xa1[2];
#pragma unroll
        for (int m = 0; m < 2; ++m) {
            short* buf = &lds[wave][m][0];
#pragma unroll
            for (int r = 0; r < 4; ++r) {
                short4 w4;
                w4.x = f2bf(fmaxf(pooled[m][0][r], 0.f));
                w4.y = f2bf(fmaxf(pooled[m][1][r], 0.f));
                w4.z = f2bf(fmaxf(pooled[m][2][r], 0.f));
                w4.w = f2bf(fmaxf(pooled[m][3][r], 0.f));
                *(short4*)(buf + (quad * 4 + r) * RS + 4 * l16) = w4;
            }
        }
#pragma unroll
        for (int m = 0; m < 2; ++m) {
            const short* buf = &lds[wave][m][0];
            xa0[m] = *(const bf16x8*)(buf + l16 * RS + quad * 8);
            xa1[m] = *(const bf16x8*)(buf + l16 * RS + 32 + quad * 8);
        }

        f32x4 h[2][4];
#pragma unroll
        for (int nt = 0; nt < 4; ++nt) {
            bf16x8 w0f = *(const bf16x8*)(wa + (nt * 16 + l16) * 64 + quad * 8);
            bf16x8 w1f = *(const bf16x8*)(wa + (nt * 16 + l16) * 64 + 32 + quad * 8);
            float bv = nt == 0 ? bai.x : nt == 1 ? bai.y : nt == 2 ? bai.z : bai.w;
#pragma unroll
            for (int m = 0; m < 2; ++m) {
                f32x4 acc = (f32x4){bv, bv, bv, bv};
                acc = __builtin_amdgcn_mfma_f32_16x16x32_bf16(xa0[m], w0f, acc, 0, 0, 0);
                acc = __builtin_amdgcn_mfma_f32_16x16x32_bf16(xa1[m], w1f, acc, 0, 0, 0);
                h[m][nt] = acc;
            }
        }

        bf16x8 ha0[2], ha1[2];
#pragma unroll
        for (int m = 0; m < 2; ++m) {
            short* buf = &lds[wave][m][0];
#pragma unroll
            for (int r = 0; r < 4; ++r) {
                short4 w4;
                w4.x = f2bf(fmaxf(h[m][0][r], 0.f));
                w4.y = f2bf(fmaxf(h[m][1][r], 0.f));
                w4.z = f2bf(fmaxf(h[m][2][r], 0.f));
                w4.w = f2bf(fmaxf(h[m][3][r], 0.f));
                *(short4*)(buf + (quad * 4 + r) * RS + 4 * l16) = w4;
            }
        }
#pragma unroll
        for (int m = 0; m < 2; ++m) {
            const short* buf = &lds[wave][m][0];
            ha0[m] = *(const bf16x8*)(buf + l16 * RS + quad * 8);
            ha1[m] = *(const bf16x8*)(buf + l16 * RS + 32 + quad * 8);
        }

#pragma unroll
        for (int nt = 0; nt < 4; ++nt) {
            bf16x8 w0f = *(const bf16x8*)(wb + (nt * 16 + l16) * 64 + quad * 8);
            bf16x8 w1f = *(const bf16x8*)(wb + (nt * 16 + l16) * 64 + 32 + quad * 8);
            float bv = nt == 0 ? bbi.x : nt == 1 ? bbi.y : nt == 2 ? bbi.z : bbi.w;
#pragma unroll
            for (int m = 0; m < 2; ++m) {
                f32x4 acc = pooled[m][nt];
#pragma unroll
                for (int r = 0; r < 4; ++r) acc[r] += bv;
                acc = __builtin_amdgcn_mfma_f32_16x16x32_bf16(ha0[m], w0f, acc, 0, 0, 0);
                acc = __builtin_amdgcn_mfma_f32_16x16x32_bf16(ha1[m], w1f, acc, 0, 0, 0);
                pooled[m][nt] = acc;
            }
        }
    }

    // =============== head ===================================================
    const float4 wo4 = *(const float4*)(Wout + 4 * l16);
    const float bo = bout[0];
#pragma unroll
    for (int m = 0; m < 2; ++m) {
        float o[4];
#pragma unroll
        for (int r = 0; r < 4; ++r) {
            float v = fmaxf(pooled[m][0][r], 0.f) * wo4.x
                    + fmaxf(pooled[m][1][r], 0.f) * wo4.y
                    + fmaxf(pooled[m][2][r], 0.f) * wo4.z
                    + fmaxf(pooled[m][3][r], 0.f) * wo4.w;
            v += __shfl_xor(v, 1);
            v += __shfl_xor(v, 2);
            v += __shfl_xor(v, 4);
            v += __shfl_xor(v, 8);
            o[r] = v + bo;
        }
        if (l16 == 0) {
            *(float4*)(out + (size_t)b * P + base + m * 16 + quad * 4) =
                make_float4(o[0], o[1], o[2], o[3]);
        }
    }
}

extern "C" void kernel_launch(void* const* d_in, const int* in_sizes, int n_in,
                              void* d_out, int out_size, void* d_ws, size_t ws_size,
                              hipStream_t stream) {
    const float* z      = (const float*)d_in[0];
    const float* pos    = (const float*)d_in[1];
    const float* p      = (const float*)d_in[2];
    const float* W_feat = (const float*)d_in[3];
    const float* W_dir  = (const float*)d_in[4];
    const float* W0     = (const float*)d_in[5];
    const float* b0     = (const float*)d_in[6];
    const float* Wa     = (const float*)d_in[7];
    const float* ba     = (const float*)d_in[8];
    const float* Wb     = (const float*)d_in[9];
    const float* bb     = (const float*)d_in[10];
    const float* Wout   = (const float*)d_in[11];
    const float* bout   = (const float*)d_in[12];
    float* out = (float*)d_out;

    short* wsS = (short*)d_ws;
    short* Bxt = wsS;                    // B*C*64*64 shorts
    short* Wat = wsS + 32 * 4096;        // 5*4096
    short* Wbt = Wat + 5 * 4096;         // 5*4096

    setup_kernel<<<112, 256, 0, stream>>>(z, W_dir, W0, b0, Wa, Wb, Bxt, Wat, Wbt);

    dim3 grid(P / 128, B);
    main_kernel<<<grid, 256, 0, stream>>>(p, pos, W_feat, Bxt, Wat, Wbt,
                                          ba, bb, Wout, bout, out);
}